// Round 9
// baseline (170.355 us; speedup 1.0000x reference)
//
#include <hip/hip_runtime.h>

// Problem constants (fixed by setup_inputs)
constexpr int B_  = 8;
constexpr int NI  = 4096;
constexpr int NT  = 512;
constexpr int CD  = 1024;

constexpr int BM   = 64;        // img rows per block
constexpr int BK   = 32;        // K per chunk = one mfma_16x16x32 K-step
constexpr int NCH  = CD / BK;   // 32 chunks
constexpr int MAXC = 512;       // candidate list capacity per block
constexpr float DELTA = 0.02f;  // ~20 sigma of fp16 approx error; mean top-2 gap ~0.28

// A-LDS geometry: 128 planes (chunk*4+q), each 64 rows x 16 B, skewed +16 B
constexpr int APLANE  = 1040;
constexpr int NPLANES = NCH * 4;            // 128
constexpr int A_BYTES = NPLANES * APLANE;   // 133120

typedef __attribute__((ext_vector_type(4))) float    f32x4;
typedef __attribute__((ext_vector_type(4))) _Float16 f16x4;
typedef __attribute__((ext_vector_type(8))) _Float16 f16x8;

// workspace layout
constexpr size_t WS_NORM_B = 16384;                      // inv_norm (4096 f32)
constexpr size_t WSB_BYTES = (size_t)B_ * NT * CD * 2;   // 8 MB fp16 text, chunk+q major
constexpr size_t NEED_B    = WS_NORM_B + WSB_BYTES;

__device__ __forceinline__ f16x4 cvt4(float4 v) {
    f16x4 h;
    h[0] = (_Float16)v.x; h[1] = (_Float16)v.y;
    h[2] = (_Float16)v.z; h[3] = (_Float16)v.w;
    return h;
}

// Kernel 1: inv text norms (reduce bit-identical to R1 — refine replicates R1
// fp32 values whose argmax matched np exactly, proven R3-R8) + fp16 pre-scaled
// text, chunk-major q-major: slab(b,kc) = [q:4][t:512][8 halfs] dense (32 KB).
template<bool PRE>
__global__ __launch_bounds__(256) void prep_text_kernel(const float* __restrict__ text,
                                                        float* __restrict__ inv_norm,
                                                        _Float16* __restrict__ wsB) {
    int row  = blockIdx.x * 4 + (threadIdx.x >> 6);
    int lane = threadIdx.x & 63;
    const float* p = text + (size_t)row * CD;
    float s = 0.f;
#pragma unroll
    for (int it = 0; it < 4; ++it) {
        int k = (lane + it * 64) * 4;
        float4 v = *reinterpret_cast<const float4*>(p + k);
        s = fmaf(v.x, v.x, s); s = fmaf(v.y, v.y, s);
        s = fmaf(v.z, v.z, s); s = fmaf(v.w, v.w, s);
    }
#pragma unroll
    for (int off = 32; off > 0; off >>= 1) s += __shfl_xor(s, off);
    float inv = 1.f / fmaxf(sqrtf(s), 1e-12f);
    if (lane == 0) inv_norm[row] = inv;

    if (PRE) {
        // lane owns k = lane*16 .. +15 -> chunk kc = lane>>1; q0 = (lane&1)*2
        int b = row >> 9, t = row & 511;
        int kc = lane >> 1;
        int q0 = (lane & 1) * 2;
        _Float16* slab = wsB + ((size_t)b * 32 + kc) * 16384;
        const float* src = p + lane * 16;
        f16x8 h0, h1;
#pragma unroll
        for (int j = 0; j < 2; ++j) {
            float4 v = *reinterpret_cast<const float4*>(src + j * 4);
            h0[j * 4 + 0] = (_Float16)(v.x * inv); h0[j * 4 + 1] = (_Float16)(v.y * inv);
            h0[j * 4 + 2] = (_Float16)(v.z * inv); h0[j * 4 + 3] = (_Float16)(v.w * inv);
        }
#pragma unroll
        for (int j = 0; j < 2; ++j) {
            float4 v = *reinterpret_cast<const float4*>(src + 8 + j * 4);
            h1[j * 4 + 0] = (_Float16)(v.x * inv); h1[j * 4 + 1] = (_Float16)(v.y * inv);
            h1[j * 4 + 2] = (_Float16)(v.z * inv); h1[j * 4 + 3] = (_Float16)(v.w * inv);
        }
        *reinterpret_cast<f16x8*>(slab + ((q0    ) * 512 + t) * 8) = h0;
        *reinterpret_cast<f16x8*>(slab + ((q0 + 1) * 512 + t) * 8) = h1;
    }
}

struct SmemE {
    float pval[8 * BM];
    int   pidx[8 * BM];
    float sval[BM];
    int   sidx[BM];
    int   rowcnt[BM];
    unsigned long long keys[BM];
    int   cand[MAXC];
    int   cnt;
};
union SmemU {
    char  a[A_BYTES];   // A fp16 planes during GEMM phase
    SmemE e;            // epilogue scratch (A dead after K-loop)
};

// Kernel 2: phase-separated fp16 MFMA sim-GEMM.
//   Phase 1: bulk row-linear load of the whole 256-KB A panel -> fp16 LDS
//            (1-KB contiguous wave sweeps; the ONLY HBM-read phase).
//   Phase 2: barrier-free fully-unrolled K-loop; A from LDS, B from L2
//            (chunk-major wsB, WS=1) or fp32 text + cvt (WS=0). Compiler
//            hoists loads across the static unroll for deep pipelining.
//   Phase 3: approx argmax + candidate filter + exact fp32 refine + gather.
// 512 thr = 8 waves; wave w owns 64 rows x 64-text slice.
template<int WS>
__global__ __launch_bounds__(512, 2) void align_kernel(const float* __restrict__ img,
                                                       const float* __restrict__ text,
                                                       const float* __restrict__ inv_norm,
                                                       const _Float16* __restrict__ wsB,
                                                       float* __restrict__ out) {
    __shared__ SmemU sm;

    const int tid = threadIdx.x;
    const int l   = tid & 63;
    const int w   = tid >> 6;      // wave = 64-text slice (0..7)
    const int q   = l >> 4;        // quarter-wave -> k-slice q*8
    const int ln  = l & 15;

    // XCD swizzle: blockIdx%8 ~ XCD id -> per-XCD L2 holds one batch's slab
    const int b    = blockIdx.x & 7;
    const int row0 = (blockIdx.x >> 3) * BM;

    const float* imgBase  = img  + ((size_t)b * NI + row0) * CD;
    const float* textBase = text + (size_t)b * NT * CD;
    const _Float16* bSlabC = wsB + (size_t)b * 32 * 16384;   // halfs

    // ---- Phase 1: A panel -> LDS (row-linear 1-KB wave sweeps) ----
    {
        const float4* panel4 = reinterpret_cast<const float4*>(imgBase);
#pragma unroll 1
        for (int bt = 0; bt < 4; ++bt) {
            float4 v[8];
#pragma unroll
            for (int j = 0; j < 8; ++j)
                v[j] = panel4[(bt * 8 + j) * 512 + tid];
#pragma unroll
            for (int j = 0; j < 8; ++j) {
                int f   = (bt * 8 + j) * 512 + tid;  // float4 index in panel
                int row = f >> 8;                    // 256 float4 per row
                int rem = f & 255;                   // plane = rem>>1, half = rem&1
                *reinterpret_cast<f16x4*>(
                    &sm.a[(rem >> 1) * APLANE + row * 16 + (rem & 1) * 8]) = cvt4(v[j]);
            }
        }
    }

    float invn4[4];
    if (!WS) {
#pragma unroll
        for (int nj = 0; nj < 4; ++nj)
            invn4[nj] = inv_norm[b * NT + w * 64 + nj * 16 + ln];
    }

    f32x4 acc[4][4];
#pragma unroll
    for (int mi = 0; mi < 4; ++mi)
#pragma unroll
        for (int nj = 0; nj < 4; ++nj) acc[mi][nj] = (f32x4)0.f;

    __syncthreads();   // A panel ready; no more barriers until epilogue

    // ---- Phase 2: fully-unrolled barrier-free K-loop ----
#pragma unroll
    for (int c = 0; c < NCH; ++c) {
        f16x8 bF[4];
        if (WS) {
            const _Float16* slab = bSlabC + (size_t)c * 16384;
#pragma unroll
            for (int nj = 0; nj < 4; ++nj)
                bF[nj] = *reinterpret_cast<const f16x8*>(
                    slab + ((size_t)q * 512 + w * 64 + nj * 16 + ln) * 8);
        } else {
#pragma unroll
            for (int nj = 0; nj < 4; ++nj) {
                const float* bp = textBase + (size_t)(w * 64 + nj * 16 + ln) * CD + c * BK + q * 8;
                float4 v0 = *reinterpret_cast<const float4*>(bp);
                float4 v1 = *reinterpret_cast<const float4*>(bp + 4);
                float sj = invn4[nj];
                f16x8 t;
                t[0] = (_Float16)(v0.x * sj); t[1] = (_Float16)(v0.y * sj);
                t[2] = (_Float16)(v0.z * sj); t[3] = (_Float16)(v0.w * sj);
                t[4] = (_Float16)(v1.x * sj); t[5] = (_Float16)(v1.y * sj);
                t[6] = (_Float16)(v1.z * sj); t[7] = (_Float16)(v1.w * sj);
                bF[nj] = t;
            }
        }
        f16x8 aF[4];
#pragma unroll
        for (int mi = 0; mi < 4; ++mi)
            aF[mi] = *reinterpret_cast<const f16x8*>(
                &sm.a[(c * 4 + q) * APLANE + (mi * 16 + ln) * 16]);
#pragma unroll
        for (int nj = 0; nj < 4; ++nj)
#pragma unroll
            for (int mi = 0; mi < 4; ++mi)
                acc[mi][nj] = __builtin_amdgcn_mfma_f32_16x16x32_f16(aF[mi], bF[nj],
                                                                     acc[mi][nj], 0, 0, 0);
    }

    __syncthreads();   // all A-LDS reads done -> safe to reuse LDS as epilogue scratch

    // ---- Phase 3: epilogue (verbatim R8 structure) ----
    // approx argmax per row WITH index (first-occurrence tie rule)
    // C/D layout: col = ln (text), row = q*4 + r  [m89]
#pragma unroll
    for (int mi = 0; mi < 4; ++mi) {
#pragma unroll
        for (int r = 0; r < 4; ++r) {
            float m  = acc[mi][0][r];
            int   bi = w * 64 + ln;
#pragma unroll
            for (int nj = 1; nj < 4; ++nj) {
                float v = acc[mi][nj][r];
                int  ci = w * 64 + nj * 16 + ln;
                if (v > m) { m = v; bi = ci; }
            }
#pragma unroll
            for (int off = 1; off < 16; off <<= 1) {
                float om = __shfl_xor(m, off);
                int   oi = __shfl_xor(bi, off);
                if (om > m || (om == m && oi < bi)) { m = om; bi = oi; }
            }
            if (ln == 0) {
                int rl = mi * 16 + q * 4 + r;
                sm.e.pval[w * BM + rl] = m;
                sm.e.pidx[w * BM + rl] = bi;
            }
        }
    }
    __syncthreads();

    // merge 8 slices (ascending w = ascending text -> first-occurrence holds)
    if (tid < BM) {
        float bv = sm.e.pval[tid];
        int   bi = sm.e.pidx[tid];
#pragma unroll
        for (int ww = 1; ww < 8; ++ww) {
            float v  = sm.e.pval[ww * BM + tid];
            int   i2 = sm.e.pidx[ww * BM + tid];
            if (v > bv || (v == bv && i2 < bi)) { bv = v; bi = i2; }
        }
        sm.e.sval[tid]   = bv;
        sm.e.sidx[tid]   = bi;    // exact answer if rowcnt==1
        sm.e.rowcnt[tid] = 0;
        sm.e.keys[tid]   = 0ull;
    }
    if (tid == 0) sm.e.cnt = 0;
    __syncthreads();

    // candidate collection: all (row,t) with approx >= rowmax - DELTA
    {
        float thr[4][4];
#pragma unroll
        for (int mi = 0; mi < 4; ++mi)
#pragma unroll
            for (int r = 0; r < 4; ++r)
                thr[mi][r] = sm.e.sval[mi * 16 + q * 4 + r] - DELTA;
#pragma unroll
        for (int mi = 0; mi < 4; ++mi)
#pragma unroll
            for (int nj = 0; nj < 4; ++nj)
#pragma unroll
                for (int r = 0; r < 4; ++r) {
                    if (acc[mi][nj][r] >= thr[mi][r]) {
                        int rl = mi * 16 + q * 4 + r;
                        int t  = w * 64 + nj * 16 + ln;
                        atomicAdd(&sm.e.rowcnt[rl], 1);
                        int slot = atomicAdd(&sm.e.cnt, 1);
                        if (slot < MAXC) sm.e.cand[slot] = (rl << 16) | t;
                    }
                }
    }
    __syncthreads();

    // exact fp32 refine, only rows with >=2 candidates (replicates R1
    // arithmetic exactly -> matches np argmax; proven R3-R8)
    {
        int n = sm.e.cnt < MAXC ? sm.e.cnt : MAXC;
        for (int c = tid; c < n; c += 512) {
            int rt = sm.e.cand[c];
            int rl = rt >> 16;
            int t  = rt & 0xFFFF;
            if (sm.e.rowcnt[rl] < 2) continue;
            const float* ap = imgBase  + (size_t)rl * CD;
            const float* bp = textBase + (size_t)t  * CD;
            float s = inv_norm[b * NT + t];
            float accv = 0.f;
#pragma unroll 2
            for (int k = 0; k < CD; k += 4) {
                float4 av = *reinterpret_cast<const float4*>(ap + k);
                float4 bv = *reinterpret_cast<const float4*>(bp + k);
                accv = fmaf(av.x, bv.x * s, accv);
                accv = fmaf(av.y, bv.y * s, accv);
                accv = fmaf(av.z, bv.z * s, accv);
                accv = fmaf(av.w, bv.w * s, accv);
            }
            unsigned ub = __float_as_uint(accv);
            unsigned su = ub ^ ((unsigned)((int)ub >> 31) | 0x80000000u);
            unsigned long long key =
                ((unsigned long long)su << 32) | (unsigned)(NT - 1 - t);
            atomicMax(&sm.e.keys[rl], key);
        }
    }
    __syncthreads();

    if (tid < BM && sm.e.rowcnt[tid] > 1)
        sm.e.sidx[tid] = NT - 1 - (int)(sm.e.keys[tid] & 0xFFFFFFFFull);
    __syncthreads();

    // gather: wave w copies rows w*8 .. w*8+7, batched 2 rows (8 loads in flight)
    float* outBase = out + ((size_t)b * NI + row0) * CD;
#pragma unroll 1
    for (int rr = 0; rr < 8; rr += 2) {
        int r0 = w * 8 + rr, r1 = r0 + 1;
        const float4* s0 = reinterpret_cast<const float4*>(textBase + (size_t)sm.e.sidx[r0] * CD);
        const float4* s1 = reinterpret_cast<const float4*>(textBase + (size_t)sm.e.sidx[r1] * CD);
        float4 v0[4], v1[4];
#pragma unroll
        for (int i = 0; i < 4; ++i) v0[i] = s0[l + 64 * i];
#pragma unroll
        for (int i = 0; i < 4; ++i) v1[i] = s1[l + 64 * i];
        float4* d0 = reinterpret_cast<float4*>(outBase + (size_t)r0 * CD);
        float4* d1 = reinterpret_cast<float4*>(outBase + (size_t)r1 * CD);
#pragma unroll
        for (int i = 0; i < 4; ++i) d0[l + 64 * i] = v0[i];
#pragma unroll
        for (int i = 0; i < 4; ++i) d1[l + 64 * i] = v1[i];
    }
}

extern "C" void kernel_launch(void* const* d_in, const int* in_sizes, int n_in,
                              void* d_out, int out_size, void* d_ws, size_t ws_size,
                              hipStream_t stream) {
    const float* img  = (const float*)d_in[0];   // [8,4096,1024] fp32
    const float* text = (const float*)d_in[1];   // [8,512,1024] fp32
    float* out      = (float*)d_out;             // [8,4096,1024] fp32
    float* inv_norm = (float*)d_ws;
    _Float16* wsB   = (_Float16*)((char*)d_ws + WS_NORM_B);

    const int gridAlign = NI / BM * B_;   // 512
    if (ws_size >= NEED_B) {
        prep_text_kernel<true><<<dim3(B_ * NT / 4), 256, 0, stream>>>(text, inv_norm, wsB);
        align_kernel<1><<<dim3(gridAlign), 512, 0, stream>>>(img, text, inv_norm, wsB, out);
    } else {
        prep_text_kernel<false><<<dim3(B_ * NT / 4), 256, 0, stream>>>(text, inv_norm, wsB);
        align_kernel<0><<<dim3(gridAlign), 512, 0, stream>>>(img, text, inv_norm, wsB, out);
    }
}

// Round 10
// 139.033 us; speedup vs baseline: 1.2253x; 1.2253x over previous
//
#include <hip/hip_runtime.h>

// Problem constants (fixed by setup_inputs)
constexpr int B_  = 8;
constexpr int NI  = 4096;
constexpr int NT  = 512;
constexpr int CD  = 1024;

constexpr int BM   = 64;        // img rows per block
constexpr int BK   = 32;        // K per chunk = one mfma_16x16x32 K-step
constexpr int NCH  = CD / BK;   // 32 chunks
constexpr int MAXC = 512;       // candidate list capacity per block
constexpr float DELTA = 0.02f;  // ~20 sigma of fp16 approx error; mean top-2 gap ~0.28

typedef __attribute__((ext_vector_type(4))) float    f32x4;
typedef __attribute__((ext_vector_type(4))) _Float16 f16x4;
typedef __attribute__((ext_vector_type(8))) _Float16 f16x8;

// workspace layout: [inv_norm 16K][sidx 128K][wsB 8M]
constexpr size_t WS_NORM_B = 16384;
constexpr size_t WS_IDX_B  = (size_t)B_ * NI * 4;        // 131072
constexpr size_t WSB_OFF   = WS_NORM_B + WS_IDX_B;
constexpr size_t WSB_BYTES = (size_t)B_ * NT * CD * 2;   // 8 MB fp16 text, chunk+q major
constexpr size_t NEED_FULL = WSB_OFF + WSB_BYTES;

__device__ __forceinline__ void gl_lds16(const void* g, void* l) {
    __builtin_amdgcn_global_load_lds(
        (const __attribute__((address_space(1))) unsigned int*)g,
        (__attribute__((address_space(3))) unsigned int*)l,
        16, 0, 0);
}

__device__ __forceinline__ f16x4 cvt4(float4 v) {
    f16x4 h;
    h[0] = (_Float16)v.x; h[1] = (_Float16)v.y;
    h[2] = (_Float16)v.z; h[3] = (_Float16)v.w;
    return h;
}

// Kernel 1: inv text norms (reduce bit-identical to R1 — refine replicates R1
// fp32 values whose argmax matched np exactly, proven R3-R9) + fp16 pre-scaled
// text, chunk-major q-major: slab(b,kc) = [q:4][t:512][8 halfs] dense (32 KB)
// = exact linear LDS image for global_load_lds.
template<bool PRE>
__global__ __launch_bounds__(256) void prep_text_kernel(const float* __restrict__ text,
                                                        float* __restrict__ inv_norm,
                                                        _Float16* __restrict__ wsB) {
    int row  = blockIdx.x * 4 + (threadIdx.x >> 6);
    int lane = threadIdx.x & 63;
    const float* p = text + (size_t)row * CD;
    float s = 0.f;
#pragma unroll
    for (int it = 0; it < 4; ++it) {
        int k = (lane + it * 64) * 4;
        float4 v = *reinterpret_cast<const float4*>(p + k);
        s = fmaf(v.x, v.x, s); s = fmaf(v.y, v.y, s);
        s = fmaf(v.z, v.z, s); s = fmaf(v.w, v.w, s);
    }
#pragma unroll
    for (int off = 32; off > 0; off >>= 1) s += __shfl_xor(s, off);
    float inv = 1.f / fmaxf(sqrtf(s), 1e-12f);
    if (lane == 0) inv_norm[row] = inv;

    if (PRE) {
        int b = row >> 9, t = row & 511;
        int kc = lane >> 1;
        int q0 = (lane & 1) * 2;
        _Float16* slab = wsB + ((size_t)b * 32 + kc) * 16384;
        const float* src = p + lane * 16;
        f16x8 h0, h1;
#pragma unroll
        for (int j = 0; j < 2; ++j) {
            float4 v = *reinterpret_cast<const float4*>(src + j * 4);
            h0[j * 4 + 0] = (_Float16)(v.x * inv); h0[j * 4 + 1] = (_Float16)(v.y * inv);
            h0[j * 4 + 2] = (_Float16)(v.z * inv); h0[j * 4 + 3] = (_Float16)(v.w * inv);
        }
#pragma unroll
        for (int j = 0; j < 2; ++j) {
            float4 v = *reinterpret_cast<const float4*>(src + 8 + j * 4);
            h1[j * 4 + 0] = (_Float16)(v.x * inv); h1[j * 4 + 1] = (_Float16)(v.y * inv);
            h1[j * 4 + 2] = (_Float16)(v.z * inv); h1[j * 4 + 3] = (_Float16)(v.w * inv);
        }
        *reinterpret_cast<f16x8*>(slab + ((q0    ) * 512 + t) * 8) = h0;
        *reinterpret_cast<f16x8*>(slab + ((q0 + 1) * 512 + t) * 8) = h1;
    }
}

struct SmemM {
    _Float16 sB[2][4 * NT * 8];   // 65536 B : [buf][q*512+t][8 halfs]
    _Float16 sA[2][BM * BK];      //  8192 B : [buf][row][32 halfs, XOR-swizzled]
};
struct SmemE {
    float pval[8 * BM];
    int   pidx[8 * BM];
    float sval[BM];
    int   sidx[BM];
    int   rowcnt[BM];
    unsigned long long keys[BM];
    int   cand[MAXC];
    int   cnt;
};
union SmemU { SmemM m; SmemE e; };

// Kernel 2: fp16 MFMA sim-GEMM (R7's proven loop, one barrier per chunk,
// double-buffered LDS; B via global_load_lds from q-major wsB) + approx
// argmax + candidate filter + exact fp32 refine. Output: per-row argmax
// index into gsidx (NO bulk data movement — gather is a separate kernel).
// 512 thr = 8 waves; wave w owns all 64 rows x 64-text slice.
template<int WS>
__global__ __launch_bounds__(512, 4) void gemm_kernel(const float* __restrict__ img,
                                                      const float* __restrict__ text,
                                                      const float* __restrict__ inv_norm,
                                                      const _Float16* __restrict__ wsB,
                                                      int* __restrict__ gsidx) {
    __shared__ SmemU sm;

    const int tid = threadIdx.x;
    const int l   = tid & 63;
    const int w   = tid >> 6;      // wave = 64-text slice (0..7)
    const int q   = l >> 4;        // quarter-wave -> k-slice q*8
    const int ln  = l & 15;

    // XCD swizzle: blockIdx%8 ~ XCD id -> per-XCD L2 holds one batch's slab
    const int b    = blockIdx.x & 7;
    const int row0 = (blockIdx.x >> 3) * BM;

    const float* imgBase  = img  + ((size_t)b * NI + row0) * CD;
    const float* textBase = text + (size_t)b * NT * CD;

    // A staging: thread -> (row = tid>>3, 16-B seg = tid&7); wave reads 8
    // contiguous 128-B row segments (coalesced).
    const int arow = tid >> 3, seg = tid & 7;
    const int aswz = (arow >> 1) & 3;                       // XOR swizzle key
    const int aOff = arow * 64 + ((seg * 8) ^ (aswz << 4)); // byte off in sA buf
    const float* aSrc = imgBase + (size_t)arow * CD + seg * 4;

    // B source slab for this batch (WS=1)
    const char* bSlab = (const char*)(wsB + (size_t)b * 32 * 16384);

    float invT = 0.f;
    if (!WS) invT = inv_norm[b * NT + tid];   // fallback: thread stages text row tid

    f32x4 acc[4][4];
#pragma unroll
    for (int mi = 0; mi < 4; ++mi)
#pragma unroll
        for (int nj = 0; nj < 4; ++nj) acc[mi][nj] = (f32x4)0.f;

    // ---- prologue: stage chunk 0 into buf 0 ----
    {
        if (WS) {
#pragma unroll
            for (int i = 0; i < 4; ++i)
                gl_lds16(bSlab + (w * 4 + i) * 1024 + l * 16,
                         (char*)&sm.m.sB[0][0] + (w * 4 + i) * 1024);
        } else {
            const float* bp = textBase + (size_t)tid * CD;
#pragma unroll
            for (int j = 0; j < 4; ++j) {
                float4 v0 = *reinterpret_cast<const float4*>(bp + j * 8);
                float4 v1 = *reinterpret_cast<const float4*>(bp + j * 8 + 4);
                f16x8 h;
                h[0] = (_Float16)(v0.x * invT); h[1] = (_Float16)(v0.y * invT);
                h[2] = (_Float16)(v0.z * invT); h[3] = (_Float16)(v0.w * invT);
                h[4] = (_Float16)(v1.x * invT); h[5] = (_Float16)(v1.y * invT);
                h[6] = (_Float16)(v1.z * invT); h[7] = (_Float16)(v1.w * invT);
                *reinterpret_cast<f16x8*>(&sm.m.sB[0][(j * 512 + tid) * 8]) = h;
            }
        }
        float4 v = *reinterpret_cast<const float4*>(aSrc);
        *reinterpret_cast<f16x4*>((char*)&sm.m.sA[0][0] + aOff) = cvt4(v);
    }
    __syncthreads();

    // ---- main loop: one barrier per chunk (R7 structure, best measured) ----
    int buf = 0;
#pragma unroll 1
    for (int kc = 0; kc < NCH; ++kc) {
        const int nbuf = buf ^ 1;
        const bool more = (kc + 1 < NCH);
        float4 av;
        if (more) {
            av = *reinterpret_cast<const float4*>(aSrc + (kc + 1) * BK);
            if (WS) {
                const char* bs = bSlab + (size_t)(kc + 1) * 32768;
#pragma unroll
                for (int i = 0; i < 4; ++i)
                    gl_lds16(bs + (w * 4 + i) * 1024 + l * 16,
                             (char*)&sm.m.sB[nbuf][0] + (w * 4 + i) * 1024);
            }
        }

        // fragments + 16 MFMA
        f16x8 af[4], bfv[4];
#pragma unroll
        for (int mi = 0; mi < 4; ++mi) {
            int row = mi * 16 + ln;
            af[mi] = *reinterpret_cast<const f16x8*>(
                (const char*)&sm.m.sA[buf][0] + row * 64 + ((q * 16) ^ (((row >> 1) & 3) << 4)));
        }
#pragma unroll
        for (int nj = 0; nj < 4; ++nj)
            bfv[nj] = *reinterpret_cast<const f16x8*>(
                &sm.m.sB[buf][(q * 512 + (w * 64 + nj * 16 + ln)) * 8]);
#pragma unroll
        for (int nj = 0; nj < 4; ++nj)
#pragma unroll
            for (int mi = 0; mi < 4; ++mi)
                acc[mi][nj] = __builtin_amdgcn_mfma_f32_16x16x32_f16(af[mi], bfv[nj], acc[mi][nj], 0, 0, 0);

        if (more) {
            if (!WS) {
                const float* bp = textBase + (size_t)tid * CD + (kc + 1) * BK;
#pragma unroll
                for (int j = 0; j < 4; ++j) {
                    float4 v0 = *reinterpret_cast<const float4*>(bp + j * 8);
                    float4 v1 = *reinterpret_cast<const float4*>(bp + j * 8 + 4);
                    f16x8 h;
                    h[0] = (_Float16)(v0.x * invT); h[1] = (_Float16)(v0.y * invT);
                    h[2] = (_Float16)(v0.z * invT); h[3] = (_Float16)(v0.w * invT);
                    h[4] = (_Float16)(v1.x * invT); h[5] = (_Float16)(v1.y * invT);
                    h[6] = (_Float16)(v1.z * invT); h[7] = (_Float16)(v1.w * invT);
                    *reinterpret_cast<f16x8*>(&sm.m.sB[nbuf][(j * 512 + tid) * 8]) = h;
                }
            }
            *reinterpret_cast<f16x4*>((char*)&sm.m.sA[nbuf][0] + aOff) = cvt4(av);
        }
        __syncthreads();
        buf = nbuf;
    }

    // ---- epilogue (LDS union; tile buffers dead) ----
    // approx argmax per row with index (first-occurrence tie rule)
    // C/D layout: col = ln (text), row = q*4 + r  [m89]
#pragma unroll
    for (int mi = 0; mi < 4; ++mi) {
#pragma unroll
        for (int r = 0; r < 4; ++r) {
            float m  = acc[mi][0][r];
            int   bi = w * 64 + ln;
#pragma unroll
            for (int nj = 1; nj < 4; ++nj) {
                float v = acc[mi][nj][r];
                int  ci = w * 64 + nj * 16 + ln;
                if (v > m) { m = v; bi = ci; }
            }
#pragma unroll
            for (int off = 1; off < 16; off <<= 1) {
                float om = __shfl_xor(m, off);
                int   oi = __shfl_xor(bi, off);
                if (om > m || (om == m && oi < bi)) { m = om; bi = oi; }
            }
            if (ln == 0) {
                int rl = mi * 16 + q * 4 + r;
                sm.e.pval[w * BM + rl] = m;
                sm.e.pidx[w * BM + rl] = bi;
            }
        }
    }
    __syncthreads();

    // merge 8 slices (ascending w = ascending text -> first-occurrence holds)
    if (tid < BM) {
        float bv = sm.e.pval[tid];
        int   bi = sm.e.pidx[tid];
#pragma unroll
        for (int ww = 1; ww < 8; ++ww) {
            float v  = sm.e.pval[ww * BM + tid];
            int   i2 = sm.e.pidx[ww * BM + tid];
            if (v > bv || (v == bv && i2 < bi)) { bv = v; bi = i2; }
        }
        sm.e.sval[tid]   = bv;
        sm.e.sidx[tid]   = bi;    // exact answer if rowcnt==1
        sm.e.rowcnt[tid] = 0;
        sm.e.keys[tid]   = 0ull;
    }
    if (tid == 0) sm.e.cnt = 0;
    __syncthreads();

    // candidate collection: all (row,t) with approx >= rowmax - DELTA
    {
        float thr[4][4];
#pragma unroll
        for (int mi = 0; mi < 4; ++mi)
#pragma unroll
            for (int r = 0; r < 4; ++r)
                thr[mi][r] = sm.e.sval[mi * 16 + q * 4 + r] - DELTA;
#pragma unroll
        for (int mi = 0; mi < 4; ++mi)
#pragma unroll
            for (int nj = 0; nj < 4; ++nj)
#pragma unroll
                for (int r = 0; r < 4; ++r) {
                    if (acc[mi][nj][r] >= thr[mi][r]) {
                        int rl = mi * 16 + q * 4 + r;
                        int t  = w * 64 + nj * 16 + ln;
                        atomicAdd(&sm.e.rowcnt[rl], 1);
                        int slot = atomicAdd(&sm.e.cnt, 1);
                        if (slot < MAXC) sm.e.cand[slot] = (rl << 16) | t;
                    }
                }
    }
    __syncthreads();

    // exact fp32 refine, only rows with >=2 candidates (replicates R1
    // arithmetic exactly -> matches np argmax; proven R3-R9)
    {
        int n = sm.e.cnt < MAXC ? sm.e.cnt : MAXC;
        for (int c = tid; c < n; c += 512) {
            int rt = sm.e.cand[c];
            int rl = rt >> 16;
            int t  = rt & 0xFFFF;
            if (sm.e.rowcnt[rl] < 2) continue;
            const float* ap = imgBase  + (size_t)rl * CD;
            const float* bp = textBase + (size_t)t  * CD;
            float s = inv_norm[b * NT + t];
            float accv = 0.f;
#pragma unroll 2
            for (int k = 0; k < CD; k += 4) {
                float4 av = *reinterpret_cast<const float4*>(ap + k);
                float4 bv = *reinterpret_cast<const float4*>(bp + k);
                accv = fmaf(av.x, bv.x * s, accv);
                accv = fmaf(av.y, bv.y * s, accv);
                accv = fmaf(av.z, bv.z * s, accv);
                accv = fmaf(av.w, bv.w * s, accv);
            }
            unsigned ub = __float_as_uint(accv);
            unsigned su = ub ^ ((unsigned)((int)ub >> 31) | 0x80000000u);
            unsigned long long key =
                ((unsigned long long)su << 32) | (unsigned)(NT - 1 - t);
            atomicMax(&sm.e.keys[rl], key);
        }
    }
    __syncthreads();

    // write per-row winning index to global (64 ints/block)
    if (tid < BM) {
        int v = sm.e.sidx[tid];
        if (sm.e.rowcnt[tid] > 1)
            v = NT - 1 - (int)(sm.e.keys[tid] & 0xFFFFFFFFull);
        gsidx[(size_t)b * NI + row0 + tid] = v;
    }
}

// Kernel 3: pure streaming gather. Block = 16 rows; text rows L2/L3-hot,
// 64-KB coalesced float4 writes per block. 2048 blocks.
__global__ __launch_bounds__(256) void gather_kernel(const float* __restrict__ text,
                                                     const int* __restrict__ gsidx,
                                                     float* __restrict__ out) {
    __shared__ int idx[16];
    const int tid  = threadIdx.x;
    const int b    = blockIdx.x & 7;                 // XCD swizzle: batch per XCD
    const int row0 = (blockIdx.x >> 3) * 16;

    if (tid < 16) idx[tid] = gsidx[(size_t)b * NI + row0 + tid];
    __syncthreads();

    const float* textBase = text + (size_t)b * NT * CD;
    float* outBase = out + ((size_t)b * NI + row0) * CD;
#pragma unroll 1
    for (int rr = 0; rr < 16; rr += 2) {
        const float4* s0 = reinterpret_cast<const float4*>(textBase + (size_t)idx[rr]     * CD);
        const float4* s1 = reinterpret_cast<const float4*>(textBase + (size_t)idx[rr + 1] * CD);
        float4 v0 = s0[tid];
        float4 v1 = s1[tid];
        reinterpret_cast<float4*>(outBase + (size_t)(rr    ) * CD)[tid] = v0;
        reinterpret_cast<float4*>(outBase + (size_t)(rr + 1) * CD)[tid] = v1;
    }
}

extern "C" void kernel_launch(void* const* d_in, const int* in_sizes, int n_in,
                              void* d_out, int out_size, void* d_ws, size_t ws_size,
                              hipStream_t stream) {
    const float* img  = (const float*)d_in[0];   // [8,4096,1024] fp32
    const float* text = (const float*)d_in[1];   // [8,512,1024] fp32
    float* out      = (float*)d_out;             // [8,4096,1024] fp32
    float* inv_norm = (float*)d_ws;
    int*   gsidx    = (int*)((char*)d_ws + WS_NORM_B);
    _Float16* wsB   = (_Float16*)((char*)d_ws + WSB_OFF);

    const int gridGemm = NI / BM * B_;   // 512
    if (ws_size >= NEED_FULL) {
        prep_text_kernel<true><<<dim3(B_ * NT / 4), 256, 0, stream>>>(text, inv_norm, wsB);
        gemm_kernel<1><<<dim3(gridGemm), 512, 0, stream>>>(img, text, inv_norm, wsB, gsidx);
    } else {
        prep_text_kernel<false><<<dim3(B_ * NT / 4), 256, 0, stream>>>(text, inv_norm, wsB);
        gemm_kernel<0><<<dim3(gridGemm), 512, 0, stream>>>(img, text, inv_norm, wsB, gsidx);
    }
    gather_kernel<<<dim3(B_ * NI / 16), 256, 0, stream>>>(text, gsidx, out);
}

// Round 12
// 131.409 us; speedup vs baseline: 1.2964x; 1.0580x over previous
//
#include <hip/hip_runtime.h>

// Problem constants (fixed by setup_inputs)
constexpr int B_  = 8;
constexpr int NI  = 4096;
constexpr int NT  = 512;
constexpr int CD  = 1024;

constexpr int BM   = 64;        // img rows per block
constexpr int BK   = 32;        // K per chunk = one mfma_16x16x32 K-step
constexpr int NCH  = CD / BK;   // 32 chunks
constexpr int MAXC = 512;       // candidate list capacity per block
constexpr float DELTA = 0.02f;  // ~50 sigma of fp16 approx error; mean top-2 gap ~0.28

typedef __attribute__((ext_vector_type(4))) float    f32x4;
typedef __attribute__((ext_vector_type(8))) _Float16 f16x8;

// workspace layout: [inv_norm 16K][sidx 128K][wsB 8M]
constexpr size_t WS_NORM_B = 16384;
constexpr size_t WS_IDX_B  = (size_t)B_ * NI * 4;        // 131072
constexpr size_t WSB_OFF   = WS_NORM_B + WS_IDX_B;
constexpr size_t WSB_BYTES = (size_t)B_ * NT * CD * 2;   // 8 MB fp16 text, chunk+q major
constexpr size_t NEED_FULL = WSB_OFF + WSB_BYTES;

// Kernel 1: inv text norms (reduce bit-identical to R1 — refine replicates R1
// fp32 values whose argmax matched np exactly, proven R3-R10) + fp16 pre-scaled
// text, chunk-major q-major: slab(b,kc) = [q:4][t:512][8 halfs] dense (32 KB).
template<bool PRE>
__global__ __launch_bounds__(256) void prep_text_kernel(const float* __restrict__ text,
                                                        float* __restrict__ inv_norm,
                                                        _Float16* __restrict__ wsB) {
    int row  = blockIdx.x * 4 + (threadIdx.x >> 6);
    int lane = threadIdx.x & 63;
    const float* p = text + (size_t)row * CD;
    float s = 0.f;
#pragma unroll
    for (int it = 0; it < 4; ++it) {
        int k = (lane + it * 64) * 4;
        float4 v = *reinterpret_cast<const float4*>(p + k);
        s = fmaf(v.x, v.x, s); s = fmaf(v.y, v.y, s);
        s = fmaf(v.z, v.z, s); s = fmaf(v.w, v.w, s);
    }
#pragma unroll
    for (int off = 32; off > 0; off >>= 1) s += __shfl_xor(s, off);
    float inv = 1.f / fmaxf(sqrtf(s), 1e-12f);
    if (lane == 0) inv_norm[row] = inv;

    if (PRE) {
        int b = row >> 9, t = row & 511;
        int kc = lane >> 1;
        int q0 = (lane & 1) * 2;
        _Float16* slab = wsB + ((size_t)b * 32 + kc) * 16384;
        const float* src = p + lane * 16;
        f16x8 h0, h1;
#pragma unroll
        for (int j = 0; j < 2; ++j) {
            float4 v = *reinterpret_cast<const float4*>(src + j * 4);
            h0[j * 4 + 0] = (_Float16)(v.x * inv); h0[j * 4 + 1] = (_Float16)(v.y * inv);
            h0[j * 4 + 2] = (_Float16)(v.z * inv); h0[j * 4 + 3] = (_Float16)(v.w * inv);
        }
#pragma unroll
        for (int j = 0; j < 2; ++j) {
            float4 v = *reinterpret_cast<const float4*>(src + 8 + j * 4);
            h1[j * 4 + 0] = (_Float16)(v.x * inv); h1[j * 4 + 1] = (_Float16)(v.y * inv);
            h1[j * 4 + 2] = (_Float16)(v.z * inv); h1[j * 4 + 3] = (_Float16)(v.w * inv);
        }
        *reinterpret_cast<f16x8*>(slab + ((q0    ) * 512 + t) * 8) = h0;
        *reinterpret_cast<f16x8*>(slab + ((q0 + 1) * 512 + t) * 8) = h1;
    }
}

struct SmemM {
    _Float16 sA[2][BM * BK];   // 2 x 4096 B, XOR-swizzled rows
};
struct SmemE {
    float pval[4 * BM];
    int   pidx[4 * BM];
    float sval[BM];
    int   sidx[BM];
    int   rowcnt[BM];
    unsigned long long keys[BM];
    int   cand[MAXC];
    int   cnt;
};
union SmemU { SmemM m; SmemE e; };

__device__ __forceinline__ f16x8 packA(float4 a, float4 b) {
    f16x8 h;
    h[0] = (_Float16)a.x; h[1] = (_Float16)a.y; h[2] = (_Float16)a.z; h[3] = (_Float16)a.w;
    h[4] = (_Float16)b.x; h[5] = (_Float16)b.y; h[6] = (_Float16)b.z; h[7] = (_Float16)b.w;
    return h;
}

// Kernel 2: register-pipelined fp16 MFMA sim-GEMM.
//   B: L2-resident wsB -> REGISTERS, ping-pong 1 chunk ahead (no LDS, no vmcnt
//      coupling at barriers). A: 4-KB LDS dbuf, reg-prefetched 2 chunks deep.
//   Barrier = s_barrier + lgkmcnt(0) ONLY -> global loads stay in flight.
//   A-prefetch rotation (R11 bug fixed): at chunk kc, ds_write A(kc+1) from
//   aN1, shift aN1<-aN2, refill aN2 = A(kc+3).
// 256 thr = 4 waves at 2 waves/EU (256-reg budget for deep pipelining);
// wave w owns 64 rows x 128 texts (32 MFMA/chunk). Writes per-row argmax idx.
template<int WS>
__global__ __launch_bounds__(256, 2) void gemm_kernel(const float* __restrict__ img,
                                                      const float* __restrict__ text,
                                                      const float* __restrict__ inv_norm,
                                                      const _Float16* __restrict__ wsB,
                                                      int* __restrict__ gsidx) {
    __shared__ SmemU sm;

    const int tid = threadIdx.x;
    const int l   = tid & 63;
    const int w   = tid >> 6;      // wave = 128-text slice (0..3)
    const int q   = l >> 4;        // quarter-wave -> k-slice q*8
    const int ln  = l & 15;

    // XCD swizzle: blockIdx%8 ~ XCD id -> per-XCD L2 holds one batch's slab
    const int b    = blockIdx.x & 7;
    const int row0 = (blockIdx.x >> 3) * BM;

    const float* imgBase  = img  + ((size_t)b * NI + row0) * CD;
    const float* textBase = text + (size_t)b * NT * CD;
    const _Float16* slab  = wsB + (size_t)b * 32 * 16384;   // halfs

    // A staging: thread -> (row = tid>>2, 32-B seg = tid&3); wave reads 16
    // contiguous 128-B row stripes (coalesced full lines).
    const int arow = tid >> 2, aseg = tid & 3;
    const float* aSrc = imgBase + (size_t)arow * CD + aseg * 8;
    const int aOff = arow * 64 + ((aseg * 16) ^ (((arow >> 1) & 3) << 4)); // byte

    // B fragment offsets (halfs) within a chunk slab
    int boff[8];
#pragma unroll
    for (int nj = 0; nj < 8; ++nj)
        boff[nj] = (q * 512 + w * 128 + nj * 16 + ln) * 8;

    float invn8[8];
    if (!WS) {
#pragma unroll
        for (int nj = 0; nj < 8; ++nj)
            invn8[nj] = inv_norm[b * NT + w * 128 + nj * 16 + ln];
    }

    f32x4 acc[4][8];
#pragma unroll
    for (int mi = 0; mi < 4; ++mi)
#pragma unroll
        for (int nj = 0; nj < 8; ++nj) acc[mi][nj] = (f32x4)0.f;

#define LOADB(DST, KC)                                                        \
    {                                                                         \
        const _Float16* sl = slab + (size_t)(KC) * 16384;                     \
        _Pragma("unroll")                                                     \
        for (int nj = 0; nj < 8; ++nj)                                        \
            DST[nj] = *reinterpret_cast<const f16x8*>(sl + boff[nj]);         \
    }
#define LOADB_F(DST, KC)                                                      \
    {                                                                         \
        _Pragma("unroll")                                                     \
        for (int nj = 0; nj < 8; ++nj) {                                      \
            const float* bp = textBase + (size_t)(w * 128 + nj * 16 + ln) * CD \
                            + (KC) * BK + q * 8;                              \
            float4 v0 = *reinterpret_cast<const float4*>(bp);                 \
            float4 v1 = *reinterpret_cast<const float4*>(bp + 4);             \
            float sj = invn8[nj];                                             \
            f16x8 t;                                                          \
            t[0] = (_Float16)(v0.x * sj); t[1] = (_Float16)(v0.y * sj);       \
            t[2] = (_Float16)(v0.z * sj); t[3] = (_Float16)(v0.w * sj);       \
            t[4] = (_Float16)(v1.x * sj); t[5] = (_Float16)(v1.y * sj);       \
            t[6] = (_Float16)(v1.z * sj); t[7] = (_Float16)(v1.w * sj);       \
            DST[nj] = t;                                                      \
        }                                                                     \
    }
#define COMPUTE(BUF, BCUR)                                                    \
    {                                                                         \
        f16x8 af[4];                                                          \
        _Pragma("unroll")                                                     \
        for (int mi = 0; mi < 4; ++mi) {                                      \
            int row = mi * 16 + ln;                                           \
            af[mi] = *reinterpret_cast<const f16x8*>(                         \
                (const char*)&sm.m.sA[BUF][0] + row * 64 +                    \
                ((q * 16) ^ (((row >> 1) & 3) << 4)));                        \
        }                                                                     \
        _Pragma("unroll")                                                     \
        for (int nj = 0; nj < 8; ++nj)                                        \
            _Pragma("unroll")                                                 \
            for (int mi = 0; mi < 4; ++mi)                                    \
                acc[mi][nj] = __builtin_amdgcn_mfma_f32_16x16x32_f16(         \
                    af[mi], BCUR[nj], acc[mi][nj], 0, 0, 0);                  \
    }
#define BARRIER()                                                             \
    asm volatile("s_waitcnt lgkmcnt(0)" ::: "memory");                        \
    __builtin_amdgcn_sched_barrier(0);                                        \
    __builtin_amdgcn_s_barrier();                                             \
    asm volatile("" ::: "memory");

// one pipeline step for chunk KC: compute from buffer CUR with b-regs BCUR,
// load B(KC+1) into BNXT, publish A(KC+1) into buffer CUR^1, refill A(KC+3).
#define STEP(KC, CUR, BCUR, BNXT)                                             \
    {                                                                         \
        const bool mB = ((KC) + 1 < NCH);                                     \
        const bool mL = ((KC) + 3 < NCH);                                     \
        if (mB) { if (WS) { LOADB(BNXT, (KC) + 1) } else { LOADB_F(BNXT, (KC) + 1) } } \
        float4 nA0, nA1;                                                      \
        if (mL) {                                                             \
            nA0 = *reinterpret_cast<const float4*>(aSrc + ((KC) + 3) * BK);   \
            nA1 = *reinterpret_cast<const float4*>(aSrc + ((KC) + 3) * BK + 4); \
        }                                                                     \
        COMPUTE(CUR, BCUR)                                                    \
        if (mB) {                                                             \
            *reinterpret_cast<f16x8*>((char*)&sm.m.sA[(CUR) ^ 1][0] + aOff) = \
                packA(aN1a, aN1b);                                            \
            aN1a = aN2a; aN1b = aN2b;                                         \
            if (mL) { aN2a = nA0; aN2b = nA1; }                               \
        }                                                                     \
        BARRIER()                                                             \
    }

    f16x8 b0[8], b1[8];
    float4 aN1a, aN1b, aN2a, aN2b;

    // ---- prologue: A(0)->LDS0, b0=B(0), aN1=A(1), aN2=A(2) ----
    {
        float4 a0  = *reinterpret_cast<const float4*>(aSrc);
        float4 a0b = *reinterpret_cast<const float4*>(aSrc + 4);
        if (WS) { LOADB(b0, 0) } else { LOADB_F(b0, 0) }
        aN1a = *reinterpret_cast<const float4*>(aSrc + BK);
        aN1b = *reinterpret_cast<const float4*>(aSrc + BK + 4);
        aN2a = *reinterpret_cast<const float4*>(aSrc + 2 * BK);
        aN2b = *reinterpret_cast<const float4*>(aSrc + 2 * BK + 4);
        *reinterpret_cast<f16x8*>((char*)&sm.m.sA[0][0] + aOff) = packA(a0, a0b);
        BARRIER()
    }

    // ---- main loop: 16 double-steps, one lgkm-only barrier per chunk ----
#pragma unroll 1
    for (int it = 0; it < NCH / 2; ++it) {
        STEP(it * 2,     0, b0, b1)
        STEP(it * 2 + 1, 1, b1, b0)
    }
#undef LOADB
#undef LOADB_F
#undef COMPUTE
#undef BARRIER
#undef STEP

    __syncthreads();   // safe transition to epilogue union

    // --- approx argmax per row WITH index (first-occurrence tie rule) ---
    // C/D layout: col = ln (text), row = q*4 + r  [m89]
#pragma unroll
    for (int mi = 0; mi < 4; ++mi) {
#pragma unroll
        for (int r = 0; r < 4; ++r) {
            float m  = acc[mi][0][r];
            int   bi = w * 128 + ln;
#pragma unroll
            for (int nj = 1; nj < 8; ++nj) {
                float v = acc[mi][nj][r];
                int  ci = w * 128 + nj * 16 + ln;
                if (v > m) { m = v; bi = ci; }
            }
#pragma unroll
            for (int off = 1; off < 16; off <<= 1) {
                float om = __shfl_xor(m, off);
                int   oi = __shfl_xor(bi, off);
                if (om > m || (om == m && oi < bi)) { m = om; bi = oi; }
            }
            if (ln == 0) {
                int rl = mi * 16 + q * 4 + r;
                sm.e.pval[w * BM + rl] = m;
                sm.e.pidx[w * BM + rl] = bi;
            }
        }
    }
    __syncthreads();

    // merge 4 slices (ascending w = ascending text -> first-occurrence holds)
    if (tid < BM) {
        float bv = sm.e.pval[tid];
        int   bi = sm.e.pidx[tid];
#pragma unroll
        for (int ww = 1; ww < 4; ++ww) {
            float v  = sm.e.pval[ww * BM + tid];
            int   i2 = sm.e.pidx[ww * BM + tid];
            if (v > bv || (v == bv && i2 < bi)) { bv = v; bi = i2; }
        }
        sm.e.sval[tid]   = bv;
        sm.e.sidx[tid]   = bi;    // exact answer if rowcnt==1
        sm.e.rowcnt[tid] = 0;
        sm.e.keys[tid]   = 0ull;
    }
    if (tid == 0) sm.e.cnt = 0;
    __syncthreads();

    // candidate collection: all (row,t) with approx >= rowmax - DELTA
    {
        float thr[4][4];
#pragma unroll
        for (int mi = 0; mi < 4; ++mi)
#pragma unroll
            for (int r = 0; r < 4; ++r)
                thr[mi][r] = sm.e.sval[mi * 16 + q * 4 + r] - DELTA;
#pragma unroll
        for (int mi = 0; mi < 4; ++mi)
#pragma unroll
            for (int nj = 0; nj < 8; ++nj)
#pragma unroll
                for (int r = 0; r < 4; ++r) {
                    if (acc[mi][nj][r] >= thr[mi][r]) {
                        int rl = mi * 16 + q * 4 + r;
                        int t  = w * 128 + nj * 16 + ln;
                        atomicAdd(&sm.e.rowcnt[rl], 1);
                        int slot = atomicAdd(&sm.e.cnt, 1);
                        if (slot < MAXC) sm.e.cand[slot] = (rl << 16) | t;
                    }
                }
    }
    __syncthreads();

    // exact fp32 refine, only rows with >=2 candidates (replicates R1
    // arithmetic exactly -> matches np argmax; proven R3-R10)
    {
        int n = sm.e.cnt < MAXC ? sm.e.cnt : MAXC;
        for (int c = tid; c < n; c += 256) {
            int rt = sm.e.cand[c];
            int rl = rt >> 16;
            int t  = rt & 0xFFFF;
            if (sm.e.rowcnt[rl] < 2) continue;
            const float* ap = imgBase  + (size_t)rl * CD;
            const float* bp = textBase + (size_t)t  * CD;
            float s = inv_norm[b * NT + t];
            float accv = 0.f;
#pragma unroll 2
            for (int k = 0; k < CD; k += 4) {
                float4 av = *reinterpret_cast<const float4*>(ap + k);
                float4 bv = *reinterpret_cast<const float4*>(bp + k);
                accv = fmaf(av.x, bv.x * s, accv);
                accv = fmaf(av.y, bv.y * s, accv);
                accv = fmaf(av.z, bv.z * s, accv);
                accv = fmaf(av.w, bv.w * s, accv);
            }
            unsigned ub = __float_as_uint(accv);
            unsigned su = ub ^ ((unsigned)((int)ub >> 31) | 0x80000000u);
            unsigned long long key =
                ((unsigned long long)su << 32) | (unsigned)(NT - 1 - t);
            atomicMax(&sm.e.keys[rl], key);
        }
    }
    __syncthreads();

    // write per-row winning index to global (64 ints/block)
    if (tid < BM) {
        int v = sm.e.sidx[tid];
        if (sm.e.rowcnt[tid] > 1)
            v = NT - 1 - (int)(sm.e.keys[tid] & 0xFFFFFFFFull);
        gsidx[(size_t)b * NI + row0 + tid] = v;
    }
}

// Kernel 3: pure streaming gather. Block = 16 rows; text rows L2/L3-hot,
// 64-KB coalesced float4 writes per block. 2048 blocks.
__global__ __launch_bounds__(256) void gather_kernel(const float* __restrict__ text,
                                                     const int* __restrict__ gsidx,
                                                     float* __restrict__ out) {
    __shared__ int idx[16];
    const int tid  = threadIdx.x;
    const int b    = blockIdx.x & 7;                 // XCD swizzle: batch per XCD
    const int row0 = (blockIdx.x >> 3) * 16;

    if (tid < 16) idx[tid] = gsidx[(size_t)b * NI + row0 + tid];
    __syncthreads();

    const float* textBase = text + (size_t)b * NT * CD;
    float* outBase = out + ((size_t)b * NI + row0) * CD;
#pragma unroll 1
    for (int rr = 0; rr < 16; rr += 2) {
        const float4* s0 = reinterpret_cast<const float4*>(textBase + (size_t)idx[rr]     * CD);
        const float4* s1 = reinterpret_cast<const float4*>(textBase + (size_t)idx[rr + 1] * CD);
        float4 v0 = s0[tid];
        float4 v1 = s1[tid];
        reinterpret_cast<float4*>(outBase + (size_t)(rr    ) * CD)[tid] = v0;
        reinterpret_cast<float4*>(outBase + (size_t)(rr + 1) * CD)[tid] = v1;
    }
}

extern "C" void kernel_launch(void* const* d_in, const int* in_sizes, int n_in,
                              void* d_out, int out_size, void* d_ws, size_t ws_size,
                              hipStream_t stream) {
    const float* img  = (const float*)d_in[0];   // [8,4096,1024] fp32
    const float* text = (const float*)d_in[1];   // [8,512,1024] fp32
    float* out      = (float*)d_out;             // [8,4096,1024] fp32
    float* inv_norm = (float*)d_ws;
    int*   gsidx    = (int*)((char*)d_ws + WS_NORM_B);
    _Float16* wsB   = (_Float16*)((char*)d_ws + WSB_OFF);

    const int gridGemm = NI / BM * B_;   // 512
    if (ws_size >= NEED_FULL) {
        prep_text_kernel<true><<<dim3(B_ * NT / 4), 256, 0, stream>>>(text, inv_norm, wsB);
        gemm_kernel<1><<<dim3(gridGemm), 256, 0, stream>>>(img, text, inv_norm, wsB, gsidx);
    } else {
        prep_text_kernel<false><<<dim3(B_ * NT / 4), 256, 0, stream>>>(text, inv_norm, wsB);
        gemm_kernel<0><<<dim3(gridGemm), 256, 0, stream>>>(img, text, inv_norm, wsB, gsidx);
    }
    gather_kernel<<<dim3(B_ * NI / 16), 256, 0, stream>>>(text, gsidx, out);
}